// Round 9
// baseline (306.069 us; speedup 1.0000x reference)
//
#include <hip/hip_runtime.h>
#include <math.h>
#include <stdint.h>

// ---------------------------------------------------------------------------
// fp16 MFMA, R9.
// R8 post-mortem: BK=32 dbuf regressed (barrier drains the just-issued
// prefetch; smaller MFMA bursts; extra conflicts). Reverted to R7 2-barrier
// B-staging. New: A operand loaded DIRECT global->VGPR (wave-private rows,
// no LDS/barrier dependency, issued before the barrier so the loads overlap
// the B-DMA drain), LDS holds only B (<=16KB). Per-layer tile shapes keep
// every GEMM at >=3 blocks/CU: L1 128x128 (2x2 waves), L2 128x64 (4x1),
// L3 64x64 (2x2) -> grid 768 for all three layers.
// ---------------------------------------------------------------------------

typedef __attribute__((ext_vector_type(8))) _Float16 half8;
typedef __attribute__((ext_vector_type(4))) _Float16 half4;
typedef __attribute__((ext_vector_type(4))) float floatx4;

#define L2E  1.4426950408889634f
#define SCALE2 2.8853901817f   // 2*log2(e)

__device__ __forceinline__ float fast_tanh(float x) {
    float ax = fabsf(x);
    float e  = __expf(-2.0f * ax);
    float r  = (1.0f - e) / (1.0f + e);
    return copysignf(r, x);
}
// async global->LDS, 16B per lane; LDS dest = wave-uniform base + lane*16
__device__ __forceinline__ void gload16(const void* g, void* l) {
    __builtin_amdgcn_global_load_lds(
        (__attribute__((address_space(1))) void*)(uintptr_t)(g),
        (__attribute__((address_space(3))) void*)(unsigned int)(uintptr_t)(l),
        16, 0, 0);
}

// -------- fp32 -> fp16 convert + column stats for BOTH inputs --------------
__global__ __launch_bounds__(256) void tof16_stats_all(
        const float* __restrict__ xn, const float* __restrict__ x,
        _Float16* __restrict__ xnh, _Float16* __restrict__ xh,
        float* __restrict__ cs0, float* __restrict__ cq0,
        float* __restrict__ cs3, float* __restrict__ cq3) {
    const float* in; _Float16* out; float *cs, *cq; int r0;
    if (blockIdx.x < 256) { in = xn; out = xnh; cs = cs0; cq = cq0; r0 = blockIdx.x * 32; }
    else                  { in = x;  out = xh;  cs = cs3; cq = cq3; r0 = (blockIdx.x - 256) * 32; }
    const int c = threadIdx.x * 4;
    float s0 = 0.f, s1 = 0.f, s2 = 0.f, s3 = 0.f;
    float q0 = 0.f, q1 = 0.f, q2 = 0.f, q3 = 0.f;
    for (int r = r0; r < r0 + 32; ++r) {
        float4 v = *(const float4*)&in[(size_t)r * 1024 + c];
        half4 h;
        h[0] = (_Float16)v.x; h[1] = (_Float16)v.y;
        h[2] = (_Float16)v.z; h[3] = (_Float16)v.w;
        *(half4*)&out[(size_t)r * 1024 + c] = h;
        s0 += v.x; q0 += v.x * v.x;
        s1 += v.y; q1 += v.y * v.y;
        s2 += v.z; q2 += v.z * v.z;
        s3 += v.w; q3 += v.w * v.w;
    }
    atomicAdd(&cs[c + 0], s0); atomicAdd(&cq[c + 0], q0);
    atomicAdd(&cs[c + 1], s1); atomicAdd(&cq[c + 1], q1);
    atomicAdd(&cs[c + 2], s2); atomicAdd(&cq[c + 2], q2);
    atomicAdd(&cs[c + 3], s3); atomicAdd(&cq[c + 3], q3);
}

// -------- wprep2: BN fold (inline) + W'T = fp16(s*W)^T + bacc = t@W --------
__global__ __launch_bounds__(256) void wprep2(
        const float* __restrict__ W, const float* __restrict__ g,
        const float* __restrict__ beta,
        const float* __restrict__ csK, const float* __restrict__ cqK, float invRK,
        _Float16* __restrict__ WTk, float* __restrict__ baccK,
        const float* __restrict__ csQ, const float* __restrict__ cqQ, float invRQ,
        _Float16* __restrict__ WTq, float* __restrict__ baccQ,
        int C, int F) {
    const int z = blockIdx.z;
    const float* cs = z ? csQ : csK;
    const float* cq = z ? cqQ : cqK;
    const float invR = z ? invRQ : invRK;
    _Float16* WT = z ? WTq : WTk;
    float* bacc = z ? baccQ : baccK;

    __shared__ float sv[32], tv[32];
    __shared__ float tile[32][33];
    __shared__ float lds2[8][32];
    const int c0 = blockIdx.y * 32, f0 = blockIdx.x * 32;
    const int tx = threadIdx.x & 31, ty = threadIdx.x >> 5;   // 32x8
    if (ty == 0) {
        int c = c0 + tx;
        float mean = cs[c] * invR;
        float var  = fmaxf(cq[c] * invR - mean * mean, 0.f);
        float s    = g[c] * rsqrtf(var + 1e-5f);
        sv[tx] = s;
        tv[tx] = beta[c] - mean * s;
    }
    __syncthreads();
    float pacc = 0.f;
#pragma unroll
    for (int i = 0; i < 32; i += 8) {
        float w = W[(size_t)(c0 + ty + i) * F + f0 + tx];
        tile[ty + i][tx] = w * sv[ty + i];
        pacc += w * tv[ty + i];
    }
    lds2[ty][tx] = pacc;
    __syncthreads();
#pragma unroll
    for (int i = 0; i < 32; i += 8)
        WT[(size_t)(f0 + ty + i) * C + c0 + tx] = (_Float16)tile[tx][ty + i];
    if (ty == 0) {
        float a = 0.f;
#pragma unroll
        for (int j = 0; j < 8; ++j) a += lds2[j][tx];
        atomicAdd(&bacc[f0 + tx], a);
    }
}

// -------- combined TN fp16 MFMA GEMM (k-trunk + q-trunk in one grid) -------
// A direct global->VGPR (issued before the barrier: overlaps B-DMA drain).
// B staged to LDS (BK=64, R7 2-barrier pattern, XOR-swizzled).
// Template: BM x BN tile, WC col-wave-groups (WR = 4/WC row-groups).
// SMODE: 0 plain, 1 column stats for next BN, 2 row sumsq * log2e (||k||^2)
template <int BM, int BN, int WC>
__global__ __launch_bounds__(256, 3) void gemm_tn_tanh(
        const _Float16* __restrict__ Ak, const _Float16* __restrict__ Aq,
        const _Float16* __restrict__ WTk, const _Float16* __restrict__ WTq,
        const float* __restrict__ bias,
        const float* __restrict__ baccK, const float* __restrict__ baccQ,
        _Float16* __restrict__ Yk, _Float16* __restrict__ Yq,
        int K, int F, int smodeK, int smodeQ,
        float* __restrict__ csK, float* __restrict__ cqK,
        float* __restrict__ csQ, float* __restrict__ cqQ,
        float* __restrict__ rowsqK) {
    constexpr int WR = 4 / WC;
    constexpr int TR = BM / WR / 16;      // row tiles per wave
    constexpr int TC = BN / WC / 16;      // col tiles per wave
    __shared__ _Float16 Bs[BN * 64];      // BN rows x 64 halfs (=128B rows)
    const int tid = threadIdx.x;
    const int wv = tid >> 6, ln = tid & 63;
    const int quad = ln >> 4, l16 = ln & 15;
    const int wr = (WC == 1) ? wv : (wv >> 1);
    const int wc = (WC == 1) ? 0  : (wv & 1);

    const int nxk = 8192 / BM;
    const bool isK = (int)blockIdx.x < nxk;
    const _Float16* A  = isK ? Ak : Aq;
    const _Float16* WT = isK ? WTk : WTq;
    const float* bacc  = isK ? baccK : baccQ;
    _Float16* Y        = isK ? Yk : Yq;
    const int smode    = isK ? smodeK : smodeQ;
    float* cs = isK ? csK : csQ;
    float* cq = isK ? cqK : cqQ;
    const int i0 = (isK ? blockIdx.x : blockIdx.x - nxk) * BM;
    const int f0 = blockIdx.y * BN;

    const size_t ldbB = (size_t)K * 2;
    const char* Bbase = (const char*)(WT + (size_t)f0 * K);
    const _Float16* Awave = A + (size_t)(i0 + wr * (BM / WR)) * K;  // wave rows

    // stage B tile: BN rows x 64 halfs, XOR swizzle (R7 scheme)
    auto stageB = [&](int kb) {
#pragma unroll
        for (int s = 0; s < BN / 32; ++s) {
            int seg = s * 256 + tid;
            int row = seg >> 3, p = seg & 7;
            int lseg = (p ^ row) & 7;
            gload16(Bbase + (size_t)row * ldbB + kb + lseg * 16, (char*)Bs + seg * 16);
        }
    };

    floatx4 acc[TR][TC];
#pragma unroll
    for (int a = 0; a < TR; ++a)
#pragma unroll
        for (int b = 0; b < TC; ++b) acc[a][b] = (floatx4)0.f;

    const int niter = K >> 6;
    stageB(0);
    for (int it = 0; it < niter; ++it) {
        // A fragments for this iter: issued BEFORE the barrier -> they fly
        // while the B DMA drains at the barrier's vmcnt wait.
        half8 af[2][TR];
#pragma unroll
        for (int kk = 0; kk < 2; ++kk)
#pragma unroll
            for (int t = 0; t < TR; ++t)
                af[kk][t] = *(const half8*)(Awave + (size_t)(t * 16 + l16) * K
                                            + it * 64 + kk * 32 + quad * 8);
        __syncthreads();   // B(it) resident (also waits our A loads)
#pragma unroll
        for (int kk = 0; kk < 2; ++kk) {
            half8 bf[TC];
#pragma unroll
            for (int tc = 0; tc < TC; ++tc) {
                int rb = wc * (BN / WC) + tc * 16 + l16;
                int cb = ((kk * 4 + quad) ^ rb) & 7;
                bf[tc] = *(const half8*)((const char*)Bs + rb * 128 + cb * 16);
            }
#pragma unroll
            for (int tr = 0; tr < TR; ++tr)
#pragma unroll
                for (int tc = 0; tc < TC; ++tc)
                    acc[tr][tc] = __builtin_amdgcn_mfma_f32_16x16x32_f16(af[kk][tr], bf[tc], acc[tr][tc], 0, 0, 0);
        }
        __syncthreads();   // all waves done reading Bs
        if (it + 1 < niter) stageB((it + 1) * 128);   // 64 halfs = 128 B
    }
    // epilogue: tanh + store; keep activations for stats
#pragma unroll
    for (int tc = 0; tc < TC; ++tc) {
        int f = f0 + wc * (BN / WC) + tc * 16 + l16;
        float bb = bias[f] + bacc[f];
#pragma unroll
        for (int tr = 0; tr < TR; ++tr)
#pragma unroll
            for (int r = 0; r < 4; ++r) {
                int row = i0 + wr * (BM / WR) + tr * 16 + quad * 4 + r;
                float v = fast_tanh(acc[tr][tc][r] + bb);
                acc[tr][tc][r] = v;
                Y[(size_t)row * F + f] = (_Float16)v;
            }
    }
    if (smode == 1) {
#pragma unroll
        for (int tc = 0; tc < TC; ++tc) {
            int f = f0 + wc * (BN / WC) + tc * 16 + l16;
            float s = 0.f, q = 0.f;
#pragma unroll
            for (int tr = 0; tr < TR; ++tr)
#pragma unroll
                for (int r = 0; r < 4; ++r) {
                    float v = acc[tr][tc][r];
                    s += v; q += v * v;
                }
            s += __shfl_xor(s, 16); q += __shfl_xor(q, 16);
            s += __shfl_xor(s, 32); q += __shfl_xor(q, 32);
            if (quad == 0) {
                atomicAdd(&cs[f], s);
                atomicAdd(&cq[f], q);
            }
        }
    } else if (smode == 2) {
#pragma unroll
        for (int tr = 0; tr < TR; ++tr)
#pragma unroll
            for (int r = 0; r < 4; ++r) {
                float rq = 0.f;
#pragma unroll
                for (int tc = 0; tc < TC; ++tc) {
                    float v = acc[tr][tc][r];
                    rq += v * v;
                }
                rq += __shfl_xor(rq, 1); rq += __shfl_xor(rq, 2);
                rq += __shfl_xor(rq, 4); rq += __shfl_xor(rq, 8);
                if (l16 == 0)
                    atomicAdd(&rowsqK[i0 + wr * (BM / WR) + tr * 16 + quad * 4 + r], rq * L2E);
            }
    }
}

// -------- flash: S = Q.K^T (K=256), logits(exp2-dom) = SCALE2*S - k2s ------
// 128-row Q blocks (regs), K in 64-row chunks DOUBLE-BUFFERED (2x32KB).
// Per-lane online softmax; 16-lane merge once at end.  (unchanged from R7)
__global__ __launch_bounds__(256, 2) void flash_mfma(
        const _Float16* __restrict__ Q, const _Float16* __restrict__ K3,
        const float* __restrict__ k2s, const float* __restrict__ yv,
        float* __restrict__ pm, float* __restrict__ pl, float* __restrict__ po,
        int jlen, int nsplit) {
    __shared__ _Float16 Ts[128 * 256];   // 64 KB: Q once, then 2x 64-row K bufs
    const int tid = threadIdx.x;
    const int wv = tid >> 6, ln = tid & 63;
    const int quad = ln >> 4, l16 = ln & 15;
    const int i0 = blockIdx.x * 128;
    const int jb = blockIdx.y * jlen;
    const int nch = jlen >> 6;           // 64-row chunks

    auto stage64 = [&](const _Float16* src, int bufseg) {
        const char* sb = (const char*)src;
#pragma unroll
        for (int it = 0; it < 8; ++it) {
            int seg = it * 256 + tid;
            int row = seg >> 5, p = seg & 31;
            int lcol = (p & 24) | ((p ^ row) & 7);
            gload16(sb + (size_t)row * 512 + lcol * 16, (char*)Ts + (bufseg + seg) * 16);
        }
    };

    // ---- Q (128 rows) -> LDS -> registers ----
    stage64(Q + (size_t)i0 * 256, 0);
    stage64(Q + (size_t)(i0 + 64) * 256, 2048);
    __syncthreads();
    half8 qf[2][8];
#pragma unroll
    for (int tr = 0; tr < 2; ++tr)
#pragma unroll
        for (int k0 = 0; k0 < 8; ++k0) {
            int row = wv * 32 + tr * 16 + l16;
            int c = k0 * 4 + quad;
            int phys = (c & 24) | ((c ^ row) & 7);
            qf[tr][k0] = *(const half8*)((const char*)Ts + row * 512 + phys * 16);
        }
    asm volatile("s_waitcnt lgkmcnt(0)" ::: "memory");
    __syncthreads();     // all waves done reading Q; Ts reusable

    float mrun[2][4], lrun[2][4], orun[2][4];
#pragma unroll
    for (int tr = 0; tr < 2; ++tr)
#pragma unroll
        for (int r = 0; r < 4; ++r) { mrun[tr][r] = -INFINITY; lrun[tr][r] = 0.f; orun[tr][r] = 0.f; }

    stage64(K3 + (size_t)jb * 256, 0);
    __syncthreads();     // chunk 0 resident
    for (int jc = 0; jc < nch; ++jc) {
        const int j0 = jb + jc * 64;
        const int bseg = (jc & 1) * 2048;
        if (jc + 1 < nch) stage64(K3 + (size_t)(j0 + 64) * 256, 2048 - bseg);
        floatx4 acc[2][4];
#pragma unroll
        for (int a = 0; a < 2; ++a)
#pragma unroll
            for (int b = 0; b < 4; ++b) acc[a][b] = (floatx4)0.f;
#pragma unroll
        for (int k0 = 0; k0 < 8; ++k0) {
            half8 kf[4];
#pragma unroll
            for (int tc = 0; tc < 4; ++tc) {
                int row = tc * 16 + l16;
                int c = k0 * 4 + quad;
                int phys = (c & 24) | ((c ^ row) & 7);
                kf[tc] = *(const half8*)((const char*)Ts + bseg * 16 + row * 512 + phys * 16);
            }
#pragma unroll
            for (int tr = 0; tr < 2; ++tr)
#pragma unroll
                for (int tc = 0; tc < 4; ++tc)
                    acc[tr][tc] = __builtin_amdgcn_mfma_f32_16x16x32_f16(qf[tr][k0], kf[tc], acc[tr][tc], 0, 0, 0);
        }
        // ---- per-lane online softmax (exp2 domain) ----
        float k2v[4], yv4[4];
#pragma unroll
        for (int tc = 0; tc < 4; ++tc) {
            int j = j0 + tc * 16 + l16;
            k2v[tc] = k2s[j];
            yv4[tc] = yv[j];
        }
#pragma unroll
        for (int tr = 0; tr < 2; ++tr)
#pragma unroll
            for (int r = 0; r < 4; ++r) {
                float lg[4], mt = -INFINITY;
#pragma unroll
                for (int tc = 0; tc < 4; ++tc) {
                    lg[tc] = SCALE2 * acc[tr][tc][r] - k2v[tc];
                    mt = fmaxf(mt, lg[tc]);
                }
                float mnew = fmaxf(mrun[tr][r], mt);
                float sc = exp2f(mrun[tr][r] - mnew);   // 0 on first chunk
                float sp = 0.f, spy = 0.f;
#pragma unroll
                for (int tc = 0; tc < 4; ++tc) {
                    float p = exp2f(lg[tc] - mnew);
                    sp  += p;
                    spy += p * yv4[tc];
                }
                lrun[tr][r] = lrun[tr][r] * sc + sp;
                orun[tr][r] = orun[tr][r] * sc + spy;
                mrun[tr][r] = mnew;
            }
        __syncthreads();   // readers done with bseg; drains next chunk DMA
    }
    // ---- merge the 16 lanes' partials once ----
#pragma unroll
    for (int tr = 0; tr < 2; ++tr)
#pragma unroll
        for (int r = 0; r < 4; ++r) {
            float m = mrun[tr][r], l = lrun[tr][r], o = orun[tr][r];
#pragma unroll
            for (int s = 1; s < 16; s <<= 1) {
                float m2 = __shfl_xor(m, s);
                float l2 = __shfl_xor(l, s);
                float o2 = __shfl_xor(o, s);
                float mn = fmaxf(m, m2);
                float a = exp2f(m - mn), b = exp2f(m2 - mn);
                l = l * a + l2 * b;
                o = o * a + o2 * b;
                m = mn;
            }
            if (l16 == 0) {
                int row = i0 + wv * 32 + tr * 16 + quad * 4 + r;
                size_t idx = (size_t)row * nsplit + blockIdx.y;
                pm[idx] = m;
                pl[idx] = l;
                po[idx] = o;
            }
        }
}

// -------- combine j-split partials (exp2 domain) ---------------------------
__global__ void combine_k(const float* __restrict__ pm, const float* __restrict__ pl,
                          const float* __restrict__ po, float* __restrict__ out,
                          int B, int nsplit) {
    int i = blockIdx.x * blockDim.x + threadIdx.x;
    if (i >= B) return;
    float M = -INFINITY;
    for (int s = 0; s < nsplit; ++s) M = fmaxf(M, pm[(size_t)i * nsplit + s]);
    float L = 0.f, O = 0.f;
    for (int s = 0; s < nsplit; ++s) {
        float w = exp2f(pm[(size_t)i * nsplit + s] - M);
        L += pl[(size_t)i * nsplit + s] * w;
        O += po[(size_t)i * nsplit + s] * w;
    }
    float r = O / L;
    out[i] = fminf(fmaxf(r, 0.f), 1.f);
}

// ---------------------------------------------------------------------------
extern "C" void kernel_launch(void* const* d_in, const int* in_sizes, int n_in,
                              void* d_out, int out_size, void* d_ws, size_t ws_size,
                              hipStream_t stream) {
    const float* x   = (const float*)d_in[0];   // [4096,1024]
    const float* x_n = (const float*)d_in[1];   // [8192,1024]
    const float* y_n = (const float*)d_in[2];   // [8192,1]
    const float* Wm[3]    = {(const float*)d_in[3],  (const float*)d_in[7],  (const float*)d_in[11]};
    const float* bm[3]    = {(const float*)d_in[4],  (const float*)d_in[8],  (const float*)d_in[12]};
    const float* gm[3]    = {(const float*)d_in[5],  (const float*)d_in[9],  (const float*)d_in[13]};
    const float* betam[3] = {(const float*)d_in[6],  (const float*)d_in[10], (const float*)d_in[14]};
    (void)in_sizes; (void)n_in; (void)out_size; (void)ws_size;

    const int B = 4096, N = 8192;
    const int NSPLIT = 16;
    const size_t M1 = 1024 * 1024;

    // ---- workspace (halfs): buffers reused across layers ----
    _Float16* h0 = (_Float16*)d_ws;        // 8M halfs: xnh  -> actBk
    _Float16* h1 = h0 + 8 * M1;            // 4M halfs: xh   -> actBq
    _Float16* h2 = h1 + 4 * M1;            // 8M halfs: actAk -> k3 | q3
    _Float16* h3 = h2 + 8 * M1;            // 4M halfs: actAq
    _Float16* WTk = h3 + 4 * M1;           // 1M halfs
    _Float16* WTq = WTk + M1;              // 1M halfs
    float* fb = (float*)(WTq + M1);
    float* csA[6], *cqA[6];
    for (int i = 0; i < 6; ++i) { csA[i] = fb + i * 2048; cqA[i] = fb + i * 2048 + 1024; }
    float* baccK[3], *baccQ[3];
    for (int i = 0; i < 3; ++i) { baccK[i] = fb + 12288 + i * 1024; baccQ[i] = fb + 15360 + i * 1024; }
    float* k2n = fb + 18432;                            // 8192 (log2e-scaled)
    const size_t zero_floats = 18432 + 8192;
    float* pm = fb + zero_floats;
    float* pl = pm + (size_t)B * NSPLIT;
    float* po = pl + (size_t)B * NSPLIT;

    _Float16* xnh = h0, *xh = h1;
    _Float16* actAk = h2, *actAq = h3;
    _Float16* actBk = h0, *actBq = h1;
    _Float16* k3 = h2, *q3 = h2 + 2 * M1;

    hipMemsetAsync(fb, 0, zero_floats * sizeof(float), stream);
    tof16_stats_all<<<384, 256, 0, stream>>>(x_n, x, xnh, xh,
                                             csA[0], cqA[0], csA[3], cqA[3]);
    const float invRK = 1.0f / (float)N, invRQ = 1.0f / (float)B;

    // L1: C=1024, F=1024 ; 128x128 tiles, 2x2 waves -> grid 96x8
    wprep2<<<dim3(1024 / 32, 1024 / 32, 2), 256, 0, stream>>>(
        Wm[0], gm[0], betam[0], csA[0], cqA[0], invRK, WTk, baccK[0],
        csA[3], cqA[3], invRQ, WTq, baccQ[0], 1024, 1024);
    gemm_tn_tanh<128, 128, 2><<<dim3(96, 8), 256, 0, stream>>>(
        xnh, xh, WTk, WTq, bm[0], baccK[0], baccQ[0], actAk, actAq,
        1024, 1024, 1, 1, csA[1], cqA[1], csA[4], cqA[4], nullptr);
    // L2: C=1024, F=512 ; 128x64 tiles, 4x1 waves -> grid 96x8
    wprep2<<<dim3(512 / 32, 1024 / 32, 2), 256, 0, stream>>>(
        Wm[1], gm[1], betam[1], csA[1], cqA[1], invRK, WTk, baccK[1],
        csA[4], cqA[4], invRQ, WTq, baccQ[1], 1024, 512);
    gemm_tn_tanh<128, 64, 1><<<dim3(96, 8), 256, 0, stream>>>(
        actAk, actAq, WTk, WTq, bm[1], baccK[1], baccQ[1], actBk, actBq,
        1024, 512, 1, 1, csA[2], cqA[2], csA[5], cqA[5], nullptr);
    // L3: C=512, F=256 ; 64x64 tiles, 2x2 waves -> grid 192x4 ; k emits ||k||^2
    wprep2<<<dim3(256 / 32, 512 / 32, 2), 256, 0, stream>>>(
        Wm[2], gm[2], betam[2], csA[2], cqA[2], invRK, WTk, baccK[2],
        csA[5], cqA[5], invRQ, WTq, baccQ[2], 512, 256);
    gemm_tn_tanh<64, 64, 2><<<dim3(192, 4), 256, 0, stream>>>(
        actBk, actBq, WTk, WTq, bm[2], baccK[2], baccQ[2], k3, q3,
        512, 256, 2, 0, nullptr, nullptr, nullptr, nullptr, k2n);

    // attention
    flash_mfma<<<dim3(B / 128, NSPLIT), 256, 0, stream>>>(
        q3, k3, k2n, y_n, pm, pl, po, N / NSPLIT, NSPLIT);
    combine_k<<<B / 256, 256, 0, stream>>>(pm, pl, po, (float*)d_out, B, NSPLIT);
}

// Round 10
// 266.157 us; speedup vs baseline: 1.1500x; 1.1500x over previous
//
#include <hip/hip_runtime.h>
#include <math.h>
#include <stdint.h>

// ---------------------------------------------------------------------------
// fp16 MFMA, R10.
// R8/R9 post-mortem: both K-loop re-slicings lost to R7's plain 2-barrier
// BK=64 GEMM. Keep R7's GEMM core EXACTLY; restructure the chain instead:
//   X@(s.W) + t@W + b  ==  BN(X)@W + b
// -> BN applied to A-fragments in-register (v_pk_fma_f16, s/t from LDS table
//    computed per block from the stats). W^T is now stat-independent: one
//    upfront wtrans kernel (all 3 layers), shared by k & q trunks (better L2
//    B-tile reuse). Chain: memset/wtrans/tof16 -> G1 -> G2 -> G3 -> flash ->
//    combine (6 serialized dispatches, was 10). wprep2/bacc deleted.
// ---------------------------------------------------------------------------

typedef __attribute__((ext_vector_type(8))) _Float16 half8;
typedef __attribute__((ext_vector_type(4))) _Float16 half4;
typedef __attribute__((ext_vector_type(4))) float floatx4;

#define L2E  1.4426950408889634f
#define SCALE2 2.8853901817f   // 2*log2(e)

__device__ __forceinline__ float fast_tanh(float x) {
    float ax = fabsf(x);
    float e  = __expf(-2.0f * ax);
    float r  = (1.0f - e) / (1.0f + e);
    return copysignf(r, x);
}
// async global->LDS, 16B per lane; LDS dest = wave-uniform base + lane*16
__device__ __forceinline__ void gload16(const void* g, void* l) {
    __builtin_amdgcn_global_load_lds(
        (__attribute__((address_space(1))) void*)(uintptr_t)(g),
        (__attribute__((address_space(3))) void*)(unsigned int)(uintptr_t)(l),
        16, 0, 0);
}

// -------- fp32 -> fp16 convert + column stats for BOTH inputs --------------
__global__ __launch_bounds__(256) void tof16_stats_all(
        const float* __restrict__ xn, const float* __restrict__ x,
        _Float16* __restrict__ xnh, _Float16* __restrict__ xh,
        float* __restrict__ cs0, float* __restrict__ cq0,
        float* __restrict__ cs3, float* __restrict__ cq3) {
    const float* in; _Float16* out; float *cs, *cq; int r0;
    if (blockIdx.x < 256) { in = xn; out = xnh; cs = cs0; cq = cq0; r0 = blockIdx.x * 32; }
    else                  { in = x;  out = xh;  cs = cs3; cq = cq3; r0 = (blockIdx.x - 256) * 32; }
    const int c = threadIdx.x * 4;
    float s0 = 0.f, s1 = 0.f, s2 = 0.f, s3 = 0.f;
    float q0 = 0.f, q1 = 0.f, q2 = 0.f, q3 = 0.f;
    for (int r = r0; r < r0 + 32; ++r) {
        float4 v = *(const float4*)&in[(size_t)r * 1024 + c];
        half4 h;
        h[0] = (_Float16)v.x; h[1] = (_Float16)v.y;
        h[2] = (_Float16)v.z; h[3] = (_Float16)v.w;
        *(half4*)&out[(size_t)r * 1024 + c] = h;
        s0 += v.x; q0 += v.x * v.x;
        s1 += v.y; q1 += v.y * v.y;
        s2 += v.z; q2 += v.z * v.z;
        s3 += v.w; q3 += v.w * v.w;
    }
    atomicAdd(&cs[c + 0], s0); atomicAdd(&cq[c + 0], q0);
    atomicAdd(&cs[c + 1], s1); atomicAdd(&cq[c + 1], q1);
    atomicAdd(&cs[c + 2], s2); atomicAdd(&cq[c + 2], q2);
    atomicAdd(&cs[c + 3], s3); atomicAdd(&cq[c + 3], q3);
}

// -------- wtrans: all 3 layers' W (CxF fp32) -> WT (FxC fp16), no stats ----
__global__ __launch_bounds__(256) void wtrans(
        const float* __restrict__ W0, const float* __restrict__ W1,
        const float* __restrict__ W2,
        _Float16* __restrict__ T0, _Float16* __restrict__ T1,
        _Float16* __restrict__ T2) {
    const int z = blockIdx.z;
    const float* W = z == 0 ? W0 : (z == 1 ? W1 : W2);
    _Float16* WT   = z == 0 ? T0 : (z == 1 ? T1 : T2);
    const int C = (z == 2) ? 512 : 1024;
    const int F = (z == 0) ? 1024 : (z == 1 ? 512 : 256);
    const int f0 = blockIdx.x * 32, c0 = blockIdx.y * 32;
    if (f0 >= F || c0 >= C) return;
    __shared__ float tile[32][33];
    const int tx = threadIdx.x & 31, ty = threadIdx.x >> 5;   // 32x8
#pragma unroll
    for (int i = 0; i < 32; i += 8)
        tile[ty + i][tx] = W[(size_t)(c0 + ty + i) * F + f0 + tx];
    __syncthreads();
#pragma unroll
    for (int i = 0; i < 32; i += 8)
        WT[(size_t)(f0 + ty + i) * C + c0 + tx] = (_Float16)tile[tx][ty + i];
}

// -------- combined TN fp16 MFMA GEMM with inline BN on A -------------------
// blocks [0,64): k rows (M=8192); [64,96): q rows (M=4096). R7 core: BK=64,
// A+B global_load_lds staged, 2 barriers/iter, XOR swizzle. A-fragments get
// a' = a*s + t (packed fp16) from an LDS s/t table built from the stats.
// SMODE: 0 plain, 1 column stats for next BN, 2 row sumsq * log2e (||k||^2)
__global__ __launch_bounds__(256, 4) void gemm_bn_tanh(
        const _Float16* __restrict__ Ak, const _Float16* __restrict__ Aq,
        const _Float16* __restrict__ WT, const float* __restrict__ bias,
        const float* __restrict__ csK, const float* __restrict__ cqK, float invRK,
        const float* __restrict__ csQ, const float* __restrict__ cqQ, float invRQ,
        const float* __restrict__ g, const float* __restrict__ beta,
        _Float16* __restrict__ Yk, _Float16* __restrict__ Yq,
        int K, int F, int smodeK, int smodeQ,
        float* __restrict__ csOutK, float* __restrict__ cqOutK,
        float* __restrict__ csOutQ, float* __restrict__ cqOutQ,
        float* __restrict__ rowsqK) {
    __shared__ _Float16 As[128 * 64];   // 16 KB
    __shared__ _Float16 Bs[128 * 64];   // 16 KB
    __shared__ _Float16 svh[1024], tvh[1024];   // 4 KB BN table
    const int tid = threadIdx.x;
    const int wv = tid >> 6, ln = tid & 63;
    const int quad = ln >> 4, l16 = ln & 15;
    const int wr = wv >> 1, wc = wv & 1;

    const bool isK = blockIdx.x < 64;
    const _Float16* A  = isK ? Ak : Aq;
    const float* cs = isK ? csK : csQ;
    const float* cq = isK ? cqK : cqQ;
    const float invR = isK ? invRK : invRQ;
    _Float16* Y        = isK ? Yk : Yq;
    const int smode    = isK ? smodeK : smodeQ;
    float* csO = isK ? csOutK : csOutQ;
    float* cqO = isK ? cqOutK : cqOutQ;
    const int i0 = (isK ? blockIdx.x : blockIdx.x - 64) * 128;
    const int f0 = blockIdx.y * 128;

    // BN fold table (per block; cheap, overlaps first staging DMA)
    const size_t ldb = (size_t)K * 2;
    const char* Abase = (const char*)(A + (size_t)i0 * K);
    const char* Bbase = (const char*)(WT + (size_t)f0 * K);

    auto stage = [&](const char* src, int kb, char* dst) {
#pragma unroll
        for (int it = 0; it < 4; ++it) {
            int seg = it * 256 + tid;
            int row = seg >> 3, p = seg & 7;
            int lcol = (p ^ row) & 7;
            gload16(src + (size_t)row * ldb + kb + lcol * 16, dst + seg * 16);
        }
    };

    stage(Abase, 0, (char*)As);
    stage(Bbase, 0, (char*)Bs);
    for (int c = tid; c < K; c += 256) {
        float mean = cs[c] * invR;
        float var  = fmaxf(cq[c] * invR - mean * mean, 0.f);
        float s    = g[c] * rsqrtf(var + 1e-5f);
        svh[c] = (_Float16)s;
        tvh[c] = (_Float16)(beta[c] - mean * s);
    }

    floatx4 acc[4][4];
#pragma unroll
    for (int a = 0; a < 4; ++a)
#pragma unroll
        for (int b = 0; b < 4; ++b) acc[a][b] = (floatx4)0.f;

    const int niter = K >> 6;
    for (int it = 0; it < niter; ++it) {
        __syncthreads();   // tiles resident (and BN table on first iter)
#pragma unroll
        for (int kk = 0; kk < 2; ++kk) {
            const int kc = it * 64 + kk * 32 + quad * 8;
            half8 sv8 = *(const half8*)&svh[kc];
            half8 tv8 = *(const half8*)&tvh[kc];
            half8 af[4], bf[4];
#pragma unroll
            for (int t = 0; t < 4; ++t) {
                int ra = wr * 64 + t * 16 + l16;
                int ca = ((kk * 4 + quad) ^ ra) & 7;
                af[t] = *(const half8*)((const char*)As + ra * 128 + ca * 16);
                af[t] = af[t] * sv8 + tv8;          // inline BN (v_pk_fma_f16)
                int rb = wc * 64 + t * 16 + l16;
                int cb = ((kk * 4 + quad) ^ rb) & 7;
                bf[t] = *(const half8*)((const char*)Bs + rb * 128 + cb * 16);
            }
#pragma unroll
            for (int tr = 0; tr < 4; ++tr)
#pragma unroll
                for (int tc = 0; tc < 4; ++tc)
                    acc[tr][tc] = __builtin_amdgcn_mfma_f32_16x16x32_f16(af[tr], bf[tc], acc[tr][tc], 0, 0, 0);
        }
        __syncthreads();   // all waves done reading tiles
        if (it + 1 < niter) {
            stage(Abase, (it + 1) * 128, (char*)As);   // 64 halfs = 128 B
            stage(Bbase, (it + 1) * 128, (char*)Bs);
        }
    }
    // epilogue: tanh + store; keep activations for stats
#pragma unroll
    for (int tc = 0; tc < 4; ++tc) {
        int f = f0 + wc * 64 + tc * 16 + l16;
        float bb = bias[f];
#pragma unroll
        for (int tr = 0; tr < 4; ++tr)
#pragma unroll
            for (int r = 0; r < 4; ++r) {
                int row = i0 + wr * 64 + tr * 16 + quad * 4 + r;
                float v = fast_tanh(acc[tr][tc][r] + bb);
                acc[tr][tc][r] = v;
                Y[(size_t)row * F + f] = (_Float16)v;
            }
    }
    if (smode == 1) {
#pragma unroll
        for (int tc = 0; tc < 4; ++tc) {
            int f = f0 + wc * 64 + tc * 16 + l16;
            float s = 0.f, q = 0.f;
#pragma unroll
            for (int tr = 0; tr < 4; ++tr)
#pragma unroll
                for (int r = 0; r < 4; ++r) {
                    float v = acc[tr][tc][r];
                    s += v; q += v * v;
                }
            s += __shfl_xor(s, 16); q += __shfl_xor(q, 16);
            s += __shfl_xor(s, 32); q += __shfl_xor(q, 32);
            if (quad == 0) {
                atomicAdd(&csO[f], s);
                atomicAdd(&cqO[f], q);
            }
        }
    } else if (smode == 2) {
#pragma unroll
        for (int tr = 0; tr < 4; ++tr)
#pragma unroll
            for (int r = 0; r < 4; ++r) {
                float rq = 0.f;
#pragma unroll
                for (int tc = 0; tc < 4; ++tc) {
                    float v = acc[tr][tc][r];
                    rq += v * v;
                }
                rq += __shfl_xor(rq, 1); rq += __shfl_xor(rq, 2);
                rq += __shfl_xor(rq, 4); rq += __shfl_xor(rq, 8);
                if (l16 == 0)
                    atomicAdd(&rowsqK[i0 + wr * 64 + tr * 16 + quad * 4 + r], rq * L2E);
            }
    }
}

// -------- flash: S = Q.K^T (K=256), logits(exp2-dom) = SCALE2*S - k2s ------
// 128-row Q blocks (regs), K in 64-row chunks DOUBLE-BUFFERED (2x32KB).
// Per-lane online softmax; 16-lane merge once at end.  (unchanged from R7)
__global__ __launch_bounds__(256, 2) void flash_mfma(
        const _Float16* __restrict__ Q, const _Float16* __restrict__ K3,
        const float* __restrict__ k2s, const float* __restrict__ yv,
        float* __restrict__ pm, float* __restrict__ pl, float* __restrict__ po,
        int jlen, int nsplit) {
    __shared__ _Float16 Ts[128 * 256];   // 64 KB: Q once, then 2x 64-row K bufs
    const int tid = threadIdx.x;
    const int wv = tid >> 6, ln = tid & 63;
    const int quad = ln >> 4, l16 = ln & 15;
    const int i0 = blockIdx.x * 128;
    const int jb = blockIdx.y * jlen;
    const int nch = jlen >> 6;           // 64-row chunks

    auto stage64 = [&](const _Float16* src, int bufseg) {
        const char* sb = (const char*)src;
#pragma unroll
        for (int it = 0; it < 8; ++it) {
            int seg = it * 256 + tid;
            int row = seg >> 5, p = seg & 31;
            int lcol = (p & 24) | ((p ^ row) & 7);
            gload16(sb + (size_t)row * 512 + lcol * 16, (char*)Ts + (bufseg + seg) * 16);
        }
    };

    // ---- Q (128 rows) -> LDS -> registers ----
    stage64(Q + (size_t)i0 * 256, 0);
    stage64(Q + (size_t)(i0 + 64) * 256, 2048);
    __syncthreads();
    half8 qf[2][8];
#pragma unroll
    for (int tr = 0; tr < 2; ++tr)
#pragma unroll
        for (int k0 = 0; k0 < 8; ++k0) {
            int row = wv * 32 + tr * 16 + l16;
            int c = k0 * 4 + quad;
            int phys = (c & 24) | ((c ^ row) & 7);
            qf[tr][k0] = *(const half8*)((const char*)Ts + row * 512 + phys * 16);
        }
    asm volatile("s_waitcnt lgkmcnt(0)" ::: "memory");
    __syncthreads();     // all waves done reading Q; Ts reusable

    float mrun[2][4], lrun[2][4], orun[2][4];
#pragma unroll
    for (int tr = 0; tr < 2; ++tr)
#pragma unroll
        for (int r = 0; r < 4; ++r) { mrun[tr][r] = -INFINITY; lrun[tr][r] = 0.f; orun[tr][r] = 0.f; }

    stage64(K3 + (size_t)jb * 256, 0);
    __syncthreads();     // chunk 0 resident
    for (int jc = 0; jc < nch; ++jc) {
        const int j0 = jb + jc * 64;
        const int bseg = (jc & 1) * 2048;
        if (jc + 1 < nch) stage64(K3 + (size_t)(j0 + 64) * 256, 2048 - bseg);
        floatx4 acc[2][4];
#pragma unroll
        for (int a = 0; a < 2; ++a)
#pragma unroll
            for (int b = 0; b < 4; ++b) acc[a][b] = (floatx4)0.f;
#pragma unroll
        for (int k0 = 0; k0 < 8; ++k0) {
            half8 kf[4];
#pragma unroll
            for (int tc = 0; tc < 4; ++tc) {
                int row = tc * 16 + l16;
                int c = k0 * 4 + quad;
                int phys = (c & 24) | ((c ^ row) & 7);
                kf[tc] = *(const half8*)((const char*)Ts + bseg * 16 + row * 512 + phys * 16);
            }
#pragma unroll
            for (int tr = 0; tr < 2; ++tr)
#pragma unroll
                for (int tc = 0; tc < 4; ++tc)
                    acc[tr][tc] = __builtin_amdgcn_mfma_f32_16x16x32_f16(qf[tr][k0], kf[tc], acc[tr][tc], 0, 0, 0);
        }
        // ---- per-lane online softmax (exp2 domain) ----
        float k2v[4], yv4[4];
#pragma unroll
        for (int tc = 0; tc < 4; ++tc) {
            int j = j0 + tc * 16 + l16;
            k2v[tc] = k2s[j];
            yv4[tc] = yv[j];
        }
#pragma unroll
        for (int tr = 0; tr < 2; ++tr)
#pragma unroll
            for (int r = 0; r < 4; ++r) {
                float lg[4], mt = -INFINITY;
#pragma unroll
                for (int tc = 0; tc < 4; ++tc) {
                    lg[tc] = SCALE2 * acc[tr][tc][r] - k2v[tc];
                    mt = fmaxf(mt, lg[tc]);
                }
                float mnew = fmaxf(mrun[tr][r], mt);
                float sc = exp2f(mrun[tr][r] - mnew);   // 0 on first chunk
                float sp = 0.f, spy = 0.f;
#pragma unroll
                for (int tc = 0; tc < 4; ++tc) {
                    float p = exp2f(lg[tc] - mnew);
                    sp  += p;
                    spy += p * yv4[tc];
                }
                lrun[tr][r] = lrun[tr][r] * sc + sp;
                orun[tr][r] = orun[tr][r] * sc + spy;
                mrun[tr][r] = mnew;
            }
        __syncthreads();   // readers done with bseg; drains next chunk DMA
    }
    // ---- merge the 16 lanes' partials once ----
#pragma unroll
    for (int tr = 0; tr < 2; ++tr)
#pragma unroll
        for (int r = 0; r < 4; ++r) {
            float m = mrun[tr][r], l = lrun[tr][r], o = orun[tr][r];
#pragma unroll
            for (int s = 1; s < 16; s <<= 1) {
                float m2 = __shfl_xor(m, s);
                float l2 = __shfl_xor(l, s);
                float o2 = __shfl_xor(o, s);
                float mn = fmaxf(m, m2);
                float a = exp2f(m - mn), b = exp2f(m2 - mn);
                l = l * a + l2 * b;
                o = o * a + o2 * b;
                m = mn;
            }
            if (l16 == 0) {
                int row = i0 + wv * 32 + tr * 16 + quad * 4 + r;
                size_t idx = (size_t)row * nsplit + blockIdx.y;
                pm[idx] = m;
                pl[idx] = l;
                po[idx] = o;
            }
        }
}

// -------- combine j-split partials (exp2 domain) ---------------------------
__global__ void combine_k(const float* __restrict__ pm, const float* __restrict__ pl,
                          const float* __restrict__ po, float* __restrict__ out,
                          int B, int nsplit) {
    int i = blockIdx.x * blockDim.x + threadIdx.x;
    if (i >= B) return;
    float M = -INFINITY;
    for (int s = 0; s < nsplit; ++s) M = fmaxf(M, pm[(size_t)i * nsplit + s]);
    float L = 0.f, O = 0.f;
    for (int s = 0; s < nsplit; ++s) {
        float w = exp2f(pm[(size_t)i * nsplit + s] - M);
        L += pl[(size_t)i * nsplit + s] * w;
        O += po[(size_t)i * nsplit + s] * w;
    }
    float r = O / L;
    out[i] = fminf(fmaxf(r, 0.f), 1.f);
}

// ---------------------------------------------------------------------------
extern "C" void kernel_launch(void* const* d_in, const int* in_sizes, int n_in,
                              void* d_out, int out_size, void* d_ws, size_t ws_size,
                              hipStream_t stream) {
    const float* x   = (const float*)d_in[0];   // [4096,1024]
    const float* x_n = (const float*)d_in[1];   // [8192,1024]
    const float* y_n = (const float*)d_in[2];   // [8192,1]
    const float* Wm[3]    = {(const float*)d_in[3],  (const float*)d_in[7],  (const float*)d_in[11]};
    const float* bm[3]    = {(const float*)d_in[4],  (const float*)d_in[8],  (const float*)d_in[12]};
    const float* gm[3]    = {(const float*)d_in[5],  (const float*)d_in[9],  (const float*)d_in[13]};
    const float* betam[3] = {(const float*)d_in[6],  (const float*)d_in[10], (const float*)d_in[14]};
    (void)in_sizes; (void)n_in; (void)out_size; (void)ws_size;

    const int B = 4096, N = 8192;
    const int NSPLIT = 16;
    const size_t M1 = 1024 * 1024;

    // ---- workspace (halfs): buffers reused across layers ----
    _Float16* h0 = (_Float16*)d_ws;        // 8M halfs: xnh  -> actBk
    _Float16* h1 = h0 + 8 * M1;            // 4M halfs: xh   -> actBq
    _Float16* h2 = h1 + 4 * M1;            // 8M halfs: actAk -> k3 | q3
    _Float16* h3 = h2 + 8 * M1;            // 4M halfs: actAq
    _Float16* WT1 = h3 + 4 * M1;           // 1M halfs   (1024x1024)
    _Float16* WT2 = WT1 + M1;              // 512K halfs (512x1024)
    _Float16* WT3 = WT2 + M1 / 2;          // 128K halfs (256x512)
    float* fb = (float*)(WT3 + M1 / 8);
    // stat sets: 0 x_n, 1 act1k, 2 act2k, 3 x, 4 act1q, 5 act2q
    float* csA[6], *cqA[6];
    for (int i = 0; i < 6; ++i) { csA[i] = fb + i * 2048; cqA[i] = fb + i * 2048 + 1024; }
    float* k2n = fb + 12288;                            // 8192 (log2e-scaled)
    const size_t zero_floats = 12288 + 8192;
    float* pm = fb + zero_floats;
    float* pl = pm + (size_t)B * NSPLIT;
    float* po = pl + (size_t)B * NSPLIT;

    _Float16* xnh = h0, *xh = h1;
    _Float16* actAk = h2, *actAq = h3;
    _Float16* actBk = h0, *actBq = h1;
    _Float16* k3 = h2, *q3 = h2 + 2 * M1;

    hipMemsetAsync(fb, 0, zero_floats * sizeof(float), stream);
    wtrans<<<dim3(32, 32, 3), 256, 0, stream>>>(Wm[0], Wm[1], Wm[2], WT1, WT2, WT3);
    tof16_stats_all<<<384, 256, 0, stream>>>(x_n, x, xnh, xh,
                                             csA[0], cqA[0], csA[3], cqA[3]);
    const float invRK = 1.0f / (float)N, invRQ = 1.0f / (float)B;

    // L1: C=1024, F=1024 ; grid 96x8
    gemm_bn_tanh<<<dim3(96, 8), 256, 0, stream>>>(
        xnh, xh, WT1, bm[0],
        csA[0], cqA[0], invRK, csA[3], cqA[3], invRQ, gm[0], betam[0],
        actAk, actAq, 1024, 1024, 1, 1,
        csA[1], cqA[1], csA[4], cqA[4], nullptr);
    // L2: C=1024, F=512 ; grid 96x4
    gemm_bn_tanh<<<dim3(96, 4), 256, 0, stream>>>(
        actAk, actAq, WT2, bm[1],
        csA[1], cqA[1], invRK, csA[4], cqA[4], invRQ, gm[1], betam[1],
        actBk, actBq, 1024, 512, 1, 1,
        csA[2], cqA[2], csA[5], cqA[5], nullptr);
    // L3: C=512, F=256 ; grid 96x2 ; k emits log2e*||k||^2
    gemm_bn_tanh<<<dim3(96, 2), 256, 0, stream>>>(
        actBk, actBq, WT3, bm[2],
        csA[2], cqA[2], invRK, csA[5], cqA[5], invRQ, gm[2], betam[2],
        k3, q3, 512, 256, 2, 0,
        nullptr, nullptr, nullptr, nullptr, k2n);

    // attention
    flash_mfma<<<dim3(B / 128, NSPLIT), 256, 0, stream>>>(
        q3, k3, k2n, y_n, pm, pl, po, N / NSPLIT, NSPLIT);
    combine_k<<<B / 256, 256, 0, stream>>>(pm, pl, po, (float*)d_out, B, NSPLIT);
}

// Round 11
// 253.178 us; speedup vs baseline: 1.2089x; 1.0513x over previous
//
#include <hip/hip_runtime.h>
#include <math.h>
#include <stdint.h>

// ---------------------------------------------------------------------------
// fp16 MFMA, R11.
// R10 (266us, best) + two levers, GEMM core untouched:
// 1) G2/G3 tile shapes fixed for occupancy: templated <BM,BN> instance of the
//    SAME R10 core. G2 128x64 -> grid(96,8)=768 blk (was 384); G3 64x64 ->
//    grid(192,4)=768 blk (was 192, 0.75/CU -> half the chip idle).
// 2) Preamble fusion: tof16_stats + 3x wtrans in ONE 2048-block kernel.
// ---------------------------------------------------------------------------

typedef __attribute__((ext_vector_type(8))) _Float16 half8;
typedef __attribute__((ext_vector_type(4))) _Float16 half4;
typedef __attribute__((ext_vector_type(4))) float floatx4;

#define L2E  1.4426950408889634f
#define SCALE2 2.8853901817f   // 2*log2(e)

__device__ __forceinline__ float fast_tanh(float x) {
    float ax = fabsf(x);
    float e  = __expf(-2.0f * ax);
    float r  = (1.0f - e) / (1.0f + e);
    return copysignf(r, x);
}
// async global->LDS, 16B per lane; LDS dest = wave-uniform base + lane*16
__device__ __forceinline__ void gload16(const void* g, void* l) {
    __builtin_amdgcn_global_load_lds(
        (__attribute__((address_space(1))) void*)(uintptr_t)(g),
        (__attribute__((address_space(3))) void*)(unsigned int)(uintptr_t)(l),
        16, 0, 0);
}

// -------- preamble: fp32->fp16 convert + stats (both inputs) + 3x W^T ------
// blocks [0,256): x_n rows ; [256,384): x rows ;
// [384,1408): W1^T ; [1408,1920): W2^T ; [1920,2048): W3^T
__global__ __launch_bounds__(256) void preamble(
        const float* __restrict__ xn, const float* __restrict__ x,
        _Float16* __restrict__ xnh, _Float16* __restrict__ xh,
        float* __restrict__ cs0, float* __restrict__ cq0,
        float* __restrict__ cs3, float* __restrict__ cq3,
        const float* __restrict__ W0, const float* __restrict__ W1,
        const float* __restrict__ W2,
        _Float16* __restrict__ T0, _Float16* __restrict__ T1,
        _Float16* __restrict__ T2) {
    const int bx = blockIdx.x;
    if (bx < 384) {
        const float* in; _Float16* out; float *cs, *cq; int r0;
        if (bx < 256) { in = xn; out = xnh; cs = cs0; cq = cq0; r0 = bx * 32; }
        else          { in = x;  out = xh;  cs = cs3; cq = cq3; r0 = (bx - 256) * 32; }
        const int c = threadIdx.x * 4;
        float s0 = 0.f, s1 = 0.f, s2 = 0.f, s3 = 0.f;
        float q0 = 0.f, q1 = 0.f, q2 = 0.f, q3 = 0.f;
        for (int r = r0; r < r0 + 32; ++r) {
            float4 v = *(const float4*)&in[(size_t)r * 1024 + c];
            half4 h;
            h[0] = (_Float16)v.x; h[1] = (_Float16)v.y;
            h[2] = (_Float16)v.z; h[3] = (_Float16)v.w;
            *(half4*)&out[(size_t)r * 1024 + c] = h;
            s0 += v.x; q0 += v.x * v.x;
            s1 += v.y; q1 += v.y * v.y;
            s2 += v.z; q2 += v.z * v.z;
            s3 += v.w; q3 += v.w * v.w;
        }
        atomicAdd(&cs[c + 0], s0); atomicAdd(&cq[c + 0], q0);
        atomicAdd(&cs[c + 1], s1); atomicAdd(&cq[c + 1], q1);
        atomicAdd(&cs[c + 2], s2); atomicAdd(&cq[c + 2], q2);
        atomicAdd(&cs[c + 3], s3); atomicAdd(&cq[c + 3], q3);
    } else {
        const float* W; _Float16* WT; int C, F, f0, c0;
        if (bx < 1408) {        // W1: 1024x1024, 32x32 f/c blocks
            int idx = bx - 384;  W = W0; WT = T0; C = 1024; F = 1024;
            f0 = (idx & 31) * 32; c0 = (idx >> 5) * 32;
        } else if (bx < 1920) { // W2: 1024x512
            int idx = bx - 1408; W = W1; WT = T1; C = 1024; F = 512;
            f0 = (idx & 15) * 32; c0 = (idx >> 4) * 32;
        } else {                // W3: 512x256
            int idx = bx - 1920; W = W2; WT = T2; C = 512;  F = 256;
            f0 = (idx & 7) * 32;  c0 = (idx >> 3) * 32;
        }
        __shared__ float tile[32][33];
        const int tx = threadIdx.x & 31, ty = threadIdx.x >> 5;   // 32x8
#pragma unroll
        for (int i = 0; i < 32; i += 8)
            tile[ty + i][tx] = W[(size_t)(c0 + ty + i) * F + f0 + tx];
        __syncthreads();
#pragma unroll
        for (int i = 0; i < 32; i += 8)
            WT[(size_t)(f0 + ty + i) * C + c0 + tx] = (_Float16)tile[tx][ty + i];
    }
}

// -------- combined TN fp16 MFMA GEMM with inline BN on A -------------------
// R10 core, templated tile. blocks [0, 8192/BM): k rows; rest: q rows.
// BK=64, A+B global_load_lds staged, 2 barriers/iter, XOR swizzle.
// Waves 2x2; TR=BM/32, TC=BN/32 16x16 tiles per wave.
// SMODE: 0 plain, 1 column stats for next BN, 2 row sumsq * log2e (||k||^2)
template <int BM, int BN>
__global__ __launch_bounds__(256, 4) void gemm_bn_tanh(
        const _Float16* __restrict__ Ak, const _Float16* __restrict__ Aq,
        const _Float16* __restrict__ WT, const float* __restrict__ bias,
        const float* __restrict__ csK, const float* __restrict__ cqK, float invRK,
        const float* __restrict__ csQ, const float* __restrict__ cqQ, float invRQ,
        const float* __restrict__ g, const float* __restrict__ beta,
        _Float16* __restrict__ Yk, _Float16* __restrict__ Yq,
        int K, int F, int smodeK, int smodeQ,
        float* __restrict__ csOutK, float* __restrict__ cqOutK,
        float* __restrict__ csOutQ, float* __restrict__ cqOutQ,
        float* __restrict__ rowsqK) {
    constexpr int TR = BM / 32;
    constexpr int TC = BN / 32;
    __shared__ _Float16 As[BM * 64];
    __shared__ _Float16 Bs[BN * 64];
    __shared__ _Float16 svh[1024], tvh[1024];   // BN fold table
    const int tid = threadIdx.x;
    const int wv = tid >> 6, ln = tid & 63;
    const int quad = ln >> 4, l16 = ln & 15;
    const int wr = wv >> 1, wc = wv & 1;

    const int nxk = 8192 / BM;
    const bool isK = (int)blockIdx.x < nxk;
    const _Float16* A  = isK ? Ak : Aq;
    const float* cs = isK ? csK : csQ;
    const float* cq = isK ? cqK : cqQ;
    const float invR = isK ? invRK : invRQ;
    _Float16* Y        = isK ? Yk : Yq;
    const int smode    = isK ? smodeK : smodeQ;
    float* csO = isK ? csOutK : csOutQ;
    float* cqO = isK ? cqOutK : cqOutQ;
    const int i0 = (isK ? blockIdx.x : blockIdx.x - nxk) * BM;
    const int f0 = blockIdx.y * BN;

    const size_t ldb = (size_t)K * 2;
    const char* Abase = (const char*)(A + (size_t)i0 * K);
    const char* Bbase = (const char*)(WT + (size_t)f0 * K);

    auto stageA = [&](int kb) {
#pragma unroll
        for (int it = 0; it < BM / 32; ++it) {
            int seg = it * 256 + tid;
            int row = seg >> 3, p = seg & 7;
            int lcol = (p ^ row) & 7;
            gload16(Abase + (size_t)row * ldb + kb + lcol * 16, (char*)As + seg * 16);
        }
    };
    auto stageB = [&](int kb) {
#pragma unroll
        for (int it = 0; it < BN / 32; ++it) {
            int seg = it * 256 + tid;
            int row = seg >> 3, p = seg & 7;
            int lcol = (p ^ row) & 7;
            gload16(Bbase + (size_t)row * ldb + kb + lcol * 16, (char*)Bs + seg * 16);
        }
    };

    stageA(0);
    stageB(0);
    for (int c = tid; c < K; c += 256) {
        float mean = cs[c] * invR;
        float var  = fmaxf(cq[c] * invR - mean * mean, 0.f);
        float s    = g[c] * rsqrtf(var + 1e-5f);
        svh[c] = (_Float16)s;
        tvh[c] = (_Float16)(beta[c] - mean * s);
    }

    floatx4 acc[TR][TC];
#pragma unroll
    for (int a = 0; a < TR; ++a)
#pragma unroll
        for (int b = 0; b < TC; ++b) acc[a][b] = (floatx4)0.f;

    const int niter = K >> 6;
    for (int it = 0; it < niter; ++it) {
        __syncthreads();   // tiles resident (and BN table on first iter)
#pragma unroll
        for (int kk = 0; kk < 2; ++kk) {
            const int kc = it * 64 + kk * 32 + quad * 8;
            half8 sv8 = *(const half8*)&svh[kc];
            half8 tv8 = *(const half8*)&tvh[kc];
            half8 af[TR], bf[TC];
#pragma unroll
            for (int t = 0; t < TR; ++t) {
                int ra = wr * (BM / 2) + t * 16 + l16;
                int ca = ((kk * 4 + quad) ^ ra) & 7;
                af[t] = *(const half8*)((const char*)As + ra * 128 + ca * 16);
                af[t] = af[t] * sv8 + tv8;          // inline BN (v_pk_fma_f16)
            }
#pragma unroll
            for (int t = 0; t < TC; ++t) {
                int rb = wc * (BN / 2) + t * 16 + l16;
                int cb = ((kk * 4 + quad) ^ rb) & 7;
                bf[t] = *(const half8*)((const char*)Bs + rb * 128 + cb * 16);
            }
#pragma unroll
            for (int tr = 0; tr < TR; ++tr)
#pragma unroll
                for (int tc = 0; tc < TC; ++tc)
                    acc[tr][tc] = __builtin_amdgcn_mfma_f32_16x16x32_f16(af[tr], bf[tc], acc[tr][tc], 0, 0, 0);
        }
        __syncthreads();   // all waves done reading tiles
        if (it + 1 < niter) {
            stageA((it + 1) * 128);   // 64 halfs = 128 B
            stageB((it + 1) * 128);
        }
    }
    // epilogue: tanh + store; keep activations for stats
#pragma unroll
    for (int tc = 0; tc < TC; ++tc) {
        int f = f0 + wc * (BN / 2) + tc * 16 + l16;
        float bb = bias[f];
#pragma unroll
        for (int tr = 0; tr < TR; ++tr)
#pragma unroll
            for (int r = 0; r < 4; ++r) {
                int row = i0 + wr * (BM / 2) + tr * 16 + quad * 4 + r;
                float v = fast_tanh(acc[tr][tc][r] + bb);
                acc[tr][tc][r] = v;
                Y[(size_t)row * F + f] = (_Float16)v;
            }
    }
    if (smode == 1) {
#pragma unroll
        for (int tc = 0; tc < TC; ++tc) {
            int f = f0 + wc * (BN / 2) + tc * 16 + l16;
            float s = 0.f, q = 0.f;
#pragma unroll
            for (int tr = 0; tr < TR; ++tr)
#pragma unroll
                for (int r = 0; r < 4; ++r) {
                    float v = acc[tr][tc][r];
                    s += v; q += v * v;
                }
            s += __shfl_xor(s, 16); q += __shfl_xor(q, 16);
            s += __shfl_xor(s, 32); q += __shfl_xor(q, 32);
            if (quad == 0) {
                atomicAdd(&csO[f], s);
                atomicAdd(&cqO[f], q);
            }
        }
    } else if (smode == 2) {
#pragma unroll
        for (int tr = 0; tr < TR; ++tr)
#pragma unroll
            for (int r = 0; r < 4; ++r) {
                float rq = 0.f;
#pragma unroll
                for (int tc = 0; tc < TC; ++tc) {
                    float v = acc[tr][tc][r];
                    rq += v * v;
                }
                rq += __shfl_xor(rq, 1); rq += __shfl_xor(rq, 2);
                rq += __shfl_xor(rq, 4); rq += __shfl_xor(rq, 8);
                if (l16 == 0)
                    atomicAdd(&rowsqK[i0 + wr * (BM / 2) + tr * 16 + quad * 4 + r], rq * L2E);
            }
    }
}

// -------- flash: S = Q.K^T (K=256), logits(exp2-dom) = SCALE2*S - k2s ------
// 128-row Q blocks (regs), K in 64-row chunks DOUBLE-BUFFERED (2x32KB).
// Per-lane online softmax; 16-lane merge once at end.  (unchanged from R7)
__global__ __launch_bounds__(256, 2) void flash_mfma(
        const _Float16* __restrict__ Q, const _Float16* __restrict__ K3,
        const float* __restrict__ k2s, const float* __restrict__ yv,
        float* __restrict__ pm, float* __restrict__ pl, float* __restrict__ po,
        int jlen, int nsplit) {
    __shared__ _Float16 Ts[128 * 256];   // 64 KB: Q once, then 2x 64-row K bufs
    const int tid = threadIdx.x;
    const int wv = tid >> 6, ln = tid & 63;
    const int quad = ln >> 4, l16 = ln & 15;
    const int i0 = blockIdx.x * 128;
    const int jb = blockIdx.y * jlen;
    const int nch = jlen >> 6;           // 64-row chunks

    auto stage64 = [&](const _Float16* src, int bufseg) {
        const char* sb = (const char*)src;
#pragma unroll
        for (int it = 0; it < 8; ++it) {
            int seg = it * 256 + tid;
            int row = seg >> 5, p = seg & 31;
            int lcol = (p & 24) | ((p ^ row) & 7);
            gload16(sb + (size_t)row * 512 + lcol * 16, (char*)Ts + (bufseg + seg) * 16);
        }
    };

    // ---- Q (128 rows) -> LDS -> registers ----
    stage64(Q + (size_t)i0 * 256, 0);
    stage64(Q + (size_t)(i0 + 64) * 256, 2048);
    __syncthreads();
    half8 qf[2][8];
#pragma unroll
    for (int tr = 0; tr < 2; ++tr)
#pragma unroll
        for (int k0 = 0; k0 < 8; ++k0) {
            int row = wv * 32 + tr * 16 + l16;
            int c = k0 * 4 + quad;
            int phys = (c & 24) | ((c ^ row) & 7);
            qf[tr][k0] = *(const half8*)((const char*)Ts + row * 512 + phys * 16);
        }
    asm volatile("s_waitcnt lgkmcnt(0)" ::: "memory");
    __syncthreads();     // all waves done reading Q; Ts reusable

    float mrun[2][4], lrun[2][4], orun[2][4];
#pragma unroll
    for (int tr = 0; tr < 2; ++tr)
#pragma unroll
        for (int r = 0; r < 4; ++r) { mrun[tr][r] = -INFINITY; lrun[tr][r] = 0.f; orun[tr][r] = 0.f; }

    stage64(K3 + (size_t)jb * 256, 0);
    __syncthreads();     // chunk 0 resident
    for (int jc = 0; jc < nch; ++jc) {
        const int j0 = jb + jc * 64;
        const int bseg = (jc & 1) * 2048;
        if (jc + 1 < nch) stage64(K3 + (size_t)(j0 + 64) * 256, 2048 - bseg);
        floatx4 acc[2][4];
#pragma unroll
        for (int a = 0; a < 2; ++a)
#pragma unroll
            for (int b = 0; b < 4; ++b) acc[a][b] = (floatx4)0.f;
#pragma unroll
        for (int k0 = 0; k0 < 8; ++k0) {
            half8 kf[4];
#pragma unroll
            for (int tc = 0; tc < 4; ++tc) {
                int row = tc * 16 + l16;
                int c = k0 * 4 + quad;
                int phys = (c & 24) | ((c ^ row) & 7);
                kf[tc] = *(const half8*)((const char*)Ts + bseg * 16 + row * 512 + phys * 16);
            }
#pragma unroll
            for (int tr = 0; tr < 2; ++tr)
#pragma unroll
                for (int tc = 0; tc < 4; ++tc)
                    acc[tr][tc] = __builtin_amdgcn_mfma_f32_16x16x32_f16(qf[tr][k0], kf[tc], acc[tr][tc], 0, 0, 0);
        }
        // ---- per-lane online softmax (exp2 domain) ----
        float k2v[4], yv4[4];
#pragma unroll
        for (int tc = 0; tc < 4; ++tc) {
            int j = j0 + tc * 16 + l16;
            k2v[tc] = k2s[j];
            yv4[tc] = yv[j];
        }
#pragma unroll
        for (int tr = 0; tr < 2; ++tr)
#pragma unroll
            for (int r = 0; r < 4; ++r) {
                float lg[4], mt = -INFINITY;
#pragma unroll
                for (int tc = 0; tc < 4; ++tc) {
                    lg[tc] = SCALE2 * acc[tr][tc][r] - k2v[tc];
                    mt = fmaxf(mt, lg[tc]);
                }
                float mnew = fmaxf(mrun[tr][r], mt);
                float sc = exp2f(mrun[tr][r] - mnew);   // 0 on first chunk
                float sp = 0.f, spy = 0.f;
#pragma unroll
                for (int tc = 0; tc < 4; ++tc) {
                    float p = exp2f(lg[tc] - mnew);
                    sp  += p;
                    spy += p * yv4[tc];
                }
                lrun[tr][r] = lrun[tr][r] * sc + sp;
                orun[tr][r] = orun[tr][r] * sc + spy;
                mrun[tr][r] = mnew;
            }
        __syncthreads();   // readers done with bseg; drains next chunk DMA
    }
    // ---- merge the 16 lanes' partials once ----
#pragma unroll
    for (int tr = 0; tr < 2; ++tr)
#pragma unroll
        for (int r = 0; r < 4; ++r) {
            float m = mrun[tr][r], l = lrun[tr][r], o = orun[tr][r];
#pragma unroll
            for (int s = 1; s < 16; s <<= 1) {
                float m2 = __shfl_xor(m, s);
                float l2 = __shfl_xor(l, s);
                float o2 = __shfl_xor(o, s);
                float mn = fmaxf(m, m2);
                float a = exp2f(m - mn), b = exp2f(m2 - mn);
                l = l * a + l2 * b;
                o = o * a + o2 * b;
                m = mn;
            }
            if (l16 == 0) {
                int row = i0 + wv * 32 + tr * 16 + quad * 4 + r;
                size_t idx = (size_t)row * nsplit + blockIdx.y;
                pm[idx] = m;
                pl[idx] = l;
                po[idx] = o;
            }
        }
}

// -------- combine j-split partials (exp2 domain) ---------------------------
__global__ void combine_k(const float* __restrict__ pm, const float* __restrict__ pl,
                          const float* __restrict__ po, float* __restrict__ out,
                          int B, int nsplit) {
    int i = blockIdx.x * blockDim.x + threadIdx.x;
    if (i >= B) return;
    float M = -INFINITY;
    for (int s = 0; s < nsplit; ++s) M = fmaxf(M, pm[(size_t)i * nsplit + s]);
    float L = 0.f, O = 0.f;
    for (int s = 0; s < nsplit; ++s) {
        float w = exp2f(pm[(size_t)i * nsplit + s] - M);
        L += pl[(size_t)i * nsplit + s] * w;
        O += po[(size_t)i * nsplit + s] * w;
    }
    float r = O / L;
    out[i] = fminf(fmaxf(r, 0.f), 1.f);
}

// ---------------------------------------------------------------------------
extern "C" void kernel_launch(void* const* d_in, const int* in_sizes, int n_in,
                              void* d_out, int out_size, void* d_ws, size_t ws_size,
                              hipStream_t stream) {
    const float* x   = (const float*)d_in[0];   // [4096,1024]
    const float* x_n = (const float*)d_in[1];   // [8192,1024]
    const float* y_n = (const float*)d_in[2];   // [8192,1]
    const float* Wm[3]    = {(const float*)d_in[3],  (const float*)d_in[7],  (const float*)d_in[11]};
    const float* bm[3]    = {(const float*)d_in[4],  (const float*)d_in[8],  (const float*)d_in[12]};
    const float* gm[3]    = {(const float*)d_in[5],  (const float*)d_in[9],  (const float*)d_in[13]};
    const float* betam[3] = {(const float*)d_in[6],  (const float*)d_in[10], (const float*)d_in[14]};
    (void)in_sizes; (void)n_in; (void)out_size; (void)ws_size;

    const int B = 4096, N = 8192;
    const int NSPLIT = 16;
    const size_t M1 = 1024 * 1024;

    // ---- workspace (halfs): buffers reused across layers ----
    _Float16* h0 = (_Float16*)d_ws;        // 8M halfs: xnh  -> actBk
    _Float16* h1 = h0 + 8 * M1;            // 4M halfs: xh   -> actBq
    _Float16* h2 = h1 + 4 * M1;            // 8M halfs: actAk -> k3 | q3
    _Float16* h3 = h2 + 8 * M1;            // 4M halfs: actAq
    _Float16* WT1 = h3 + 4 * M1;           // 1M halfs   (1024x1024)
    _Float16* WT2 = WT1 + M1;              // 512K halfs (512x1024)
    _Float16* WT3 = WT2 + M1 / 2;          // 128K halfs (256x512)
    float* fb = (float*)(WT3 + M1 / 8);
    // stat sets: 0 x_n, 1 act1k, 2 act2k, 3 x, 4 act1q, 5 act2q
    float* csA[6], *cqA[6];
    for (int i = 0; i < 6; ++i) { csA[i] = fb + i * 2048; cqA[i] = fb + i * 2048 + 1024; }
    float* k2n = fb + 12288;                            // 8192 (log2e-scaled)
    const size_t zero_floats = 12288 + 8192;
    float* pm = fb + zero_floats;
    float* pl = pm + (size_t)B * NSPLIT;
    float* po = pl + (size_t)B * NSPLIT;

    _Float16* xnh = h0, *xh = h1;
    _Float16* actAk = h2, *actAq = h3;
    _Float16* actBk = h0, *actBq = h1;
    _Float16* k3 = h2, *q3 = h2 + 2 * M1;

    hipMemsetAsync(fb, 0, zero_floats * sizeof(float), stream);
    preamble<<<2048, 256, 0, stream>>>(x_n, x, xnh, xh,
                                       csA[0], cqA[0], csA[3], cqA[3],
                                       Wm[0], Wm[1], Wm[2], WT1, WT2, WT3);
    const float invRK = 1.0f / (float)N, invRQ = 1.0f / (float)B;

    // L1: C=1024, F=1024 ; 128x128 tiles, grid 96x8
    gemm_bn_tanh<128, 128><<<dim3(96, 8), 256, 0, stream>>>(
        xnh, xh, WT1, bm[0],
        csA[0], cqA[0], invRK, csA[3], cqA[3], invRQ, gm[0], betam[0],
        actAk, actAq, 1024, 1024, 1, 1,
        csA[1], cqA[1], csA[4], cqA[4], nullptr);
    // L2: C=1024, F=512 ; 128x64 tiles, grid 96x8
    gemm_bn_tanh<128, 64><<<dim3(96, 8), 256, 0, stream>>>(
        actAk, actAq, WT2, bm[1],
        csA[1], cqA[1], invRK, csA[4], cqA[4], invRQ, gm[1], betam[1],
        actBk, actBq, 1024, 512, 1, 1,
        csA[2], cqA[2], csA[5], cqA[5], nullptr);
    // L3: C=512, F=256 ; 64x64 tiles, grid 192x4 ; k emits log2e*||k||^2
    gemm_bn_tanh<64, 64><<<dim3(192, 4), 256, 0, stream>>>(
        actBk, actBq, WT3, bm[2],
        csA[2], cqA[2], invRK, csA[5], cqA[5], invRQ, gm[2], betam[2],
        k3, q3, 512, 256, 2, 0,
        nullptr, nullptr, nullptr, nullptr, k2n);

    // attention
    flash_mfma<<<dim3(B / 128, NSPLIT), 256, 0, stream>>>(
        q3, k3, k2n, y_n, pm, pl, po, N / NSPLIT, NSPLIT);
    combine_k<<<B / 256, 256, 0, stream>>>(pm, pl, po, (float*)d_out, B, NSPLIT);
}